// Round 1
// baseline (379.686 us; speedup 1.0000x reference)
//
#include <hip/hip_runtime.h>

#define T_TOK 4096
#define DIM   1024
#define FDIM  2048
#define NEXP  8

typedef unsigned short u16;
typedef unsigned int   u32;
typedef __bf16 bf16x8 __attribute__((ext_vector_type(8)));
typedef float  f32x4  __attribute__((ext_vector_type(4)));

__device__ __forceinline__ u16 f2b(float f) {
  __bf16 b = (__bf16)f;
  return __builtin_bit_cast(u16, b);
}

// XOR-swizzled byte offset within a [128 rows][128 bytes] LDS tile (64 bf16 cols).
__device__ __forceinline__ u32 swz(u32 r, u32 cb) {
  return ((r << 7) + cb) ^ ((r & 7u) << 4);
}

// ---------------- gating: logits -> softmax -> top2 ----------------
__global__ __launch_bounds__(256) void gating_kernel(
    const float* __restrict__ x, const float* __restrict__ wg,
    int* __restrict__ tokexp, float* __restrict__ tokwgt, int* __restrict__ counts)
{
  int t = blockIdx.x;
  int tid = threadIdx.x;
  const float4* xv4 = (const float4*)(x + (size_t)t * DIM);
  float4 xv = xv4[tid];
  float acc[NEXP];
#pragma unroll
  for (int e = 0; e < NEXP; ++e) {
    const float4* wv4 = (const float4*)(wg + (size_t)e * DIM);
    float4 wv = wv4[tid];
    acc[e] = xv.x * wv.x + xv.y * wv.y + xv.z * wv.z + xv.w * wv.w;
  }
#pragma unroll
  for (int e = 0; e < NEXP; ++e) {
    float v = acc[e];
    for (int s = 32; s > 0; s >>= 1) v += __shfl_down(v, s, 64);
    acc[e] = v;
  }
  __shared__ float part[NEXP][4];
  int wid = tid >> 6, lane = tid & 63;
  if (lane == 0) {
#pragma unroll
    for (int e = 0; e < NEXP; ++e) part[e][wid] = acc[e];
  }
  __syncthreads();
  if (tid == 0) {
    float l[NEXP];
    float mx = -1e30f;
#pragma unroll
    for (int e = 0; e < NEXP; ++e) {
      l[e] = part[e][0] + part[e][1] + part[e][2] + part[e][3];
      mx = fmaxf(mx, l[e]);
    }
    float p[NEXP];
    float s = 0.f;
#pragma unroll
    for (int e = 0; e < NEXP; ++e) { p[e] = expf(l[e] - mx); s += p[e]; }
    float inv = 1.f / s;
#pragma unroll
    for (int e = 0; e < NEXP; ++e) p[e] *= inv;
    int e0 = 0;
#pragma unroll
    for (int e = 1; e < NEXP; ++e) if (p[e] > p[e0]) e0 = e;
    int e1 = (e0 == 0) ? 1 : 0;
#pragma unroll
    for (int e = 0; e < NEXP; ++e) if (e != e0 && p[e] > p[e1]) e1 = e;
    tokexp[2 * t]     = e0;
    tokexp[2 * t + 1] = e1;
    tokwgt[2 * t]     = p[e0];
    tokwgt[2 * t + 1] = p[e1];
    atomicAdd(&counts[e0], 1);
    atomicAdd(&counts[e1], 1);
  }
}

__global__ void prefix_kernel(const int* __restrict__ counts, int* __restrict__ offsets) {
  if (threadIdx.x == 0) {
    int s = 0;
    for (int e = 0; e < NEXP; ++e) { offsets[e] = s; s += counts[e]; }
  }
}

__global__ __launch_bounds__(256) void scatter_kernel(
    const int* __restrict__ tokexp, const float* __restrict__ tokwgt,
    const int* __restrict__ offsets, int* __restrict__ cursor,
    int* __restrict__ tok, float* __restrict__ wgt)
{
  int t = blockIdx.x * 256 + threadIdx.x;
  if (t >= T_TOK) return;
#pragma unroll
  for (int k = 0; k < 2; ++k) {
    int e = tokexp[2 * t + k];
    int p = atomicAdd(&cursor[e], 1);
    int r = offsets[e] + p;
    tok[r] = t;
    wgt[r] = tokwgt[2 * t + k];
  }
}

// w2 [E][F][D] fp32 -> w2t [E][D][F] bf16
__global__ __launch_bounds__(256) void transpose_kernel(
    const float* __restrict__ w2, u16* __restrict__ w2t)
{
  __shared__ float tile[32][33];
  int e = blockIdx.z;
  int d0 = blockIdx.x * 32;
  int f0 = blockIdx.y * 32;
  int tx = threadIdx.x & 31;
  int ty = threadIdx.x >> 5;  // 0..7
  const float* src = w2 + ((size_t)e * FDIM + f0) * DIM + d0;
#pragma unroll
  for (int j = 0; j < 4; ++j)
    tile[ty + 8 * j][tx] = src[(size_t)(ty + 8 * j) * DIM + tx];
  __syncthreads();
  u16* dst = w2t + ((size_t)e * DIM + d0) * FDIM + f0;
#pragma unroll
  for (int j = 0; j < 4; ++j)
    dst[(size_t)(ty + 8 * j) * FDIM + tx] = f2b(tile[tx][ty + 8 * j]);
}

// ---------------- fc1: h = gelu( X_gathered @ W1[e]^T ), bf16 out ----------------
__global__ __launch_bounds__(256) void fc1_kernel(
    const float* __restrict__ x, const float* __restrict__ w1,
    const int* __restrict__ tok, const int* __restrict__ counts,
    const int* __restrict__ offsets, u16* __restrict__ h)
{
  int e = blockIdx.z;
  int Me = counts[e];
  int mbase = blockIdx.y * 128;
  if (mbase >= Me) return;
  int nbase = blockIdx.x * 128;
  int off = offsets[e];

  __shared__ u16 Als[8192];
  __shared__ u16 Bls[8192];
  __shared__ int toks[128];

  int tid = threadIdx.x;
  if (tid < 128) {
    int r = mbase + tid;
    toks[tid] = tok[off + (r < Me ? r : Me - 1)];
  }

  const float* w1e = w1 + ((size_t)e * FDIM + nbase) * DIM;

  f32x4 acc[4][4];
#pragma unroll
  for (int m = 0; m < 4; ++m)
#pragma unroll
    for (int n = 0; n < 4; ++n)
      acc[m][n] = (f32x4){0.f, 0.f, 0.f, 0.f};

  int lane = tid & 63;
  int wid = tid >> 6;
  int wr = (wid >> 1) * 64;
  int wc = (wid & 1) * 64;
  int fr = lane & 15;
  int kg = lane >> 4;

  for (int kt = 0; kt < DIM; kt += 64) {
    __syncthreads();
    // stage A (gathered x rows, fp32 -> bf16)
#pragma unroll
    for (int p = 0; p < 4; ++p) {
      int idx = p * 256 + tid;
      int r = idx >> 3;
      int c8 = (idx & 7) * 8;
      const float* src = x + (size_t)toks[r] * DIM + kt + c8;
      float4 v0 = *(const float4*)src;
      float4 v1 = *(const float4*)(src + 4);
      uint4 w;
      w.x = (u32)f2b(v0.x) | ((u32)f2b(v0.y) << 16);
      w.y = (u32)f2b(v0.z) | ((u32)f2b(v0.w) << 16);
      w.z = (u32)f2b(v1.x) | ((u32)f2b(v1.y) << 16);
      w.w = (u32)f2b(v1.z) | ((u32)f2b(v1.w) << 16);
      *(uint4*)((char*)Als + swz(r, c8 * 2)) = w;
    }
    // stage B (w1 rows, fp32 -> bf16)
#pragma unroll
    for (int p = 0; p < 4; ++p) {
      int idx = p * 256 + tid;
      int r = idx >> 3;
      int c8 = (idx & 7) * 8;
      const float* src = w1e + (size_t)r * DIM + kt + c8;
      float4 v0 = *(const float4*)src;
      float4 v1 = *(const float4*)(src + 4);
      uint4 w;
      w.x = (u32)f2b(v0.x) | ((u32)f2b(v0.y) << 16);
      w.y = (u32)f2b(v0.z) | ((u32)f2b(v0.w) << 16);
      w.z = (u32)f2b(v1.x) | ((u32)f2b(v1.y) << 16);
      w.w = (u32)f2b(v1.z) | ((u32)f2b(v1.w) << 16);
      *(uint4*)((char*)Bls + swz(r, c8 * 2)) = w;
    }
    __syncthreads();
#pragma unroll
    for (int kk = 0; kk < 2; ++kk) {
      bf16x8 af[4], bfr[4];
#pragma unroll
      for (int m = 0; m < 4; ++m)
        af[m] = *(const bf16x8*)((const char*)Als + swz(wr + m * 16 + fr, kk * 64 + kg * 16));
#pragma unroll
      for (int n = 0; n < 4; ++n)
        bfr[n] = *(const bf16x8*)((const char*)Bls + swz(wc + n * 16 + fr, kk * 64 + kg * 16));
#pragma unroll
      for (int m = 0; m < 4; ++m)
#pragma unroll
        for (int n = 0; n < 4; ++n)
          acc[m][n] = __builtin_amdgcn_mfma_f32_16x16x32_bf16(af[m], bfr[n], acc[m][n], 0, 0, 0);
    }
  }

  int rb = kg * 4;
#pragma unroll
  for (int m = 0; m < 4; ++m) {
#pragma unroll
    for (int r = 0; r < 4; ++r) {
      int row = wr + m * 16 + rb + r;
      if (mbase + row < Me) {
        u16* dst = h + (size_t)(off + mbase + row) * FDIM + nbase + wc;
#pragma unroll
        for (int n = 0; n < 4; ++n) {
          float v = acc[m][n][r];
          v = 0.5f * v * (1.f + erff(v * 0.70710678118654752f));
          dst[n * 16 + fr] = f2b(v);
        }
      }
    }
  }
}

// ---------------- fc2: y[tok] += wgt * ( H @ W2t[e]^T ) ----------------
__global__ __launch_bounds__(256) void fc2_kernel(
    const u16* __restrict__ h, const u16* __restrict__ w2t,
    const int* __restrict__ tok, const float* __restrict__ wgt,
    const int* __restrict__ counts, const int* __restrict__ offsets,
    float* __restrict__ y)
{
  int e = blockIdx.z;
  int Me = counts[e];
  int mbase = blockIdx.y * 128;
  if (mbase >= Me) return;
  int nbase = blockIdx.x * 128;
  int off = offsets[e];

  __shared__ u16 Als[8192];
  __shared__ u16 Bls[8192];
  __shared__ int toks[128];
  __shared__ float wls[128];

  int tid = threadIdx.x;
  if (tid < 128) {
    int r = mbase + tid;
    int rr = (r < Me ? r : Me - 1);
    toks[tid] = tok[off + rr];
    wls[tid] = wgt[off + rr];
  }

  const u16* w2e = w2t + ((size_t)e * DIM + nbase) * FDIM;

  f32x4 acc[4][4];
#pragma unroll
  for (int m = 0; m < 4; ++m)
#pragma unroll
    for (int n = 0; n < 4; ++n)
      acc[m][n] = (f32x4){0.f, 0.f, 0.f, 0.f};

  int lane = tid & 63;
  int wid = tid >> 6;
  int wr = (wid >> 1) * 64;
  int wc = (wid & 1) * 64;
  int fr = lane & 15;
  int kg = lane >> 4;

  for (int kt = 0; kt < FDIM; kt += 64) {
    __syncthreads();
    // stage A (h rows, already bf16)
#pragma unroll
    for (int p = 0; p < 4; ++p) {
      int idx = p * 256 + tid;
      int r = idx >> 3;
      int c8 = (idx & 7) * 8;
      int rr = (mbase + r < Me) ? r : (Me - 1 - mbase);
      uint4 v = *(const uint4*)(h + (size_t)(off + mbase + rr) * FDIM + kt + c8);
      *(uint4*)((char*)Als + swz(r, c8 * 2)) = v;
    }
    // stage B (w2t rows, bf16)
#pragma unroll
    for (int p = 0; p < 4; ++p) {
      int idx = p * 256 + tid;
      int r = idx >> 3;
      int c8 = (idx & 7) * 8;
      uint4 v = *(const uint4*)(w2e + (size_t)r * FDIM + kt + c8);
      *(uint4*)((char*)Bls + swz(r, c8 * 2)) = v;
    }
    __syncthreads();
#pragma unroll
    for (int kk = 0; kk < 2; ++kk) {
      bf16x8 af[4], bfr[4];
#pragma unroll
      for (int m = 0; m < 4; ++m)
        af[m] = *(const bf16x8*)((const char*)Als + swz(wr + m * 16 + fr, kk * 64 + kg * 16));
#pragma unroll
      for (int n = 0; n < 4; ++n)
        bfr[n] = *(const bf16x8*)((const char*)Bls + swz(wc + n * 16 + fr, kk * 64 + kg * 16));
#pragma unroll
      for (int m = 0; m < 4; ++m)
#pragma unroll
        for (int n = 0; n < 4; ++n)
          acc[m][n] = __builtin_amdgcn_mfma_f32_16x16x32_bf16(af[m], bfr[n], acc[m][n], 0, 0, 0);
    }
  }

  int rb = kg * 4;
#pragma unroll
  for (int m = 0; m < 4; ++m) {
#pragma unroll
    for (int r = 0; r < 4; ++r) {
      int row = wr + m * 16 + rb + r;
      if (mbase + row < Me) {
        float cw = wls[row];
        float* dst = y + (size_t)toks[row] * DIM + nbase + wc;
#pragma unroll
        for (int n = 0; n < 4; ++n)
          atomicAdd(&dst[n * 16 + fr], cw * acc[m][n][r]);
      }
    }
  }
}

extern "C" void kernel_launch(void* const* d_in, const int* in_sizes, int n_in,
                              void* d_out, int out_size, void* d_ws, size_t ws_size,
                              hipStream_t stream)
{
  const float* x  = (const float*)d_in[0];
  const float* wg = (const float*)d_in[1];
  const float* w1 = (const float*)d_in[2];
  const float* w2 = (const float*)d_in[3];
  float* y = (float*)d_out;

  char* ws = (char*)d_ws;
  size_t o = 0;
  u16* h      = (u16*)(ws + o);   o += (size_t)8192 * FDIM * 2;        // 33.5 MB
  u16* w2t    = (u16*)(ws + o);   o += (size_t)NEXP * DIM * FDIM * 2;  // 33.5 MB
  int*   tokexp = (int*)(ws + o); o += (size_t)T_TOK * 2 * 4;
  float* tokwgt = (float*)(ws + o); o += (size_t)T_TOK * 2 * 4;
  int*   tok    = (int*)(ws + o); o += (size_t)T_TOK * 2 * 4;
  float* wgt    = (float*)(ws + o); o += (size_t)T_TOK * 2 * 4;
  int*   counts = (int*)(ws + o); o += 32;
  int*   offsets= (int*)(ws + o); o += 32;
  int*   cursor = (int*)(ws + o); o += 32;

  hipMemsetAsync(d_out, 0, (size_t)out_size * sizeof(float), stream);
  hipMemsetAsync(counts, 0, 96, stream);

  gating_kernel<<<T_TOK, 256, 0, stream>>>(x, wg, tokexp, tokwgt, counts);
  prefix_kernel<<<1, 64, 0, stream>>>(counts, offsets);
  scatter_kernel<<<T_TOK / 256, 256, 0, stream>>>(tokexp, tokwgt, offsets, cursor, tok, wgt);
  transpose_kernel<<<dim3(DIM / 32, FDIM / 32, NEXP), 256, 0, stream>>>(w2, w2t);
  fc1_kernel<<<dim3(FDIM / 128, T_TOK / 128, NEXP), 256, 0, stream>>>(x, w1, tok, counts, offsets, h);
  fc2_kernel<<<dim3(DIM / 128, T_TOK / 128, NEXP), 256, 0, stream>>>(h, w2t, tok, wgt, counts, offsets, y);
}

// Round 2
// 362.043 us; speedup vs baseline: 1.0487x; 1.0487x over previous
//
#include <hip/hip_runtime.h>

#define T_TOK 4096
#define DIM   1024
#define FDIM  2048
#define NEXP  8

typedef unsigned short u16;
typedef unsigned int   u32;
typedef __bf16 bf16x8 __attribute__((ext_vector_type(8)));
typedef float  f32x4  __attribute__((ext_vector_type(4)));

__device__ __forceinline__ u16 f2b(float f) {
  __bf16 b = (__bf16)f;
  return __builtin_bit_cast(u16, b);
}

// async global->LDS, 16B per lane; LDS dest is wave-uniform base + lane*16
#define GLOAD16(gsrc, ldst) \
  __builtin_amdgcn_global_load_lds((const __attribute__((address_space(1))) void*)(gsrc), \
                                   (__attribute__((address_space(3))) void*)(ldst), 16, 0, 0)

// ---------------- gating: logits -> softmax -> top2 ----------------
__global__ __launch_bounds__(256) void gating_kernel(
    const float* __restrict__ x, const float* __restrict__ wg,
    int* __restrict__ tokexp, float* __restrict__ tokwgt, int* __restrict__ counts)
{
  int t = blockIdx.x;
  int tid = threadIdx.x;
  const float4* xv4 = (const float4*)(x + (size_t)t * DIM);
  float4 xv = xv4[tid];
  float acc[NEXP];
#pragma unroll
  for (int e = 0; e < NEXP; ++e) {
    const float4* wv4 = (const float4*)(wg + (size_t)e * DIM);
    float4 wv = wv4[tid];
    acc[e] = xv.x * wv.x + xv.y * wv.y + xv.z * wv.z + xv.w * wv.w;
  }
#pragma unroll
  for (int e = 0; e < NEXP; ++e) {
    float v = acc[e];
    for (int s = 32; s > 0; s >>= 1) v += __shfl_down(v, s, 64);
    acc[e] = v;
  }
  __shared__ float part[NEXP][4];
  int wid = tid >> 6, lane = tid & 63;
  if (lane == 0) {
#pragma unroll
    for (int e = 0; e < NEXP; ++e) part[e][wid] = acc[e];
  }
  __syncthreads();
  if (tid == 0) {
    float l[NEXP];
    float mx = -1e30f;
#pragma unroll
    for (int e = 0; e < NEXP; ++e) {
      l[e] = part[e][0] + part[e][1] + part[e][2] + part[e][3];
      mx = fmaxf(mx, l[e]);
    }
    float p[NEXP];
    float s = 0.f;
#pragma unroll
    for (int e = 0; e < NEXP; ++e) { p[e] = expf(l[e] - mx); s += p[e]; }
    float inv = 1.f / s;
#pragma unroll
    for (int e = 0; e < NEXP; ++e) p[e] *= inv;
    int e0 = 0;
#pragma unroll
    for (int e = 1; e < NEXP; ++e) if (p[e] > p[e0]) e0 = e;
    int e1 = (e0 == 0) ? 1 : 0;
#pragma unroll
    for (int e = 0; e < NEXP; ++e) if (e != e0 && p[e] > p[e1]) e1 = e;
    tokexp[2 * t]     = e0;
    tokexp[2 * t + 1] = e1;
    tokwgt[2 * t]     = p[e0];
    tokwgt[2 * t + 1] = p[e1];
    atomicAdd(&counts[e0], 1);
    atomicAdd(&counts[e1], 1);
  }
}

__global__ void prefix_kernel(const int* __restrict__ counts, int* __restrict__ offsets) {
  if (threadIdx.x == 0) {
    int s = 0;
    for (int e = 0; e < NEXP; ++e) { offsets[e] = s; s += counts[e]; }
  }
}

__global__ __launch_bounds__(256) void scatter_kernel(
    const int* __restrict__ tokexp,
    const int* __restrict__ offsets, int* __restrict__ cursor,
    int* __restrict__ tok, int* __restrict__ slot)
{
  int t = blockIdx.x * 256 + threadIdx.x;
  if (t >= T_TOK) return;
#pragma unroll
  for (int k = 0; k < 2; ++k) {
    int e = tokexp[2 * t + k];
    int p = atomicAdd(&cursor[e], 1);
    int r = offsets[e] + p;
    tok[r] = t;
    slot[2 * t + k] = r;
  }
}

// generic fp32 -> bf16, 8 elems/thread
__global__ __launch_bounds__(256) void convert_kernel(
    const float* __restrict__ src, u16* __restrict__ dst, int n8)
{
  int i = blockIdx.x * 256 + threadIdx.x;
  if (i >= n8) return;
  const float4* s = (const float4*)(src + (size_t)i * 8);
  float4 v0 = s[0], v1 = s[1];
  uint4 w;
  w.x = (u32)f2b(v0.x) | ((u32)f2b(v0.y) << 16);
  w.y = (u32)f2b(v0.z) | ((u32)f2b(v0.w) << 16);
  w.z = (u32)f2b(v1.x) | ((u32)f2b(v1.y) << 16);
  w.w = (u32)f2b(v1.z) | ((u32)f2b(v1.w) << 16);
  *(uint4*)(dst + (size_t)i * 8) = w;
}

// w2 [E][F][D] fp32 -> w2t [E][D][F] bf16
__global__ __launch_bounds__(256) void transpose_kernel(
    const float* __restrict__ w2, u16* __restrict__ w2t)
{
  __shared__ float tile[32][33];
  int e = blockIdx.z;
  int d0 = blockIdx.x * 32;
  int f0 = blockIdx.y * 32;
  int tx = threadIdx.x & 31;
  int ty = threadIdx.x >> 5;  // 0..7
  const float* src = w2 + ((size_t)e * FDIM + f0) * DIM + d0;
#pragma unroll
  for (int j = 0; j < 4; ++j)
    tile[ty + 8 * j][tx] = src[(size_t)(ty + 8 * j) * DIM + tx];
  __syncthreads();
  u16* dst = w2t + ((size_t)e * DIM + d0) * FDIM + f0;
#pragma unroll
  for (int j = 0; j < 4; ++j)
    dst[(size_t)(ty + 8 * j) * FDIM + tx] = f2b(tile[tx][ty + 8 * j]);
}

// ---------------- fc1: h = gelu( Xb_gathered @ W1b[e]^T ), bf16 out ----------------
__global__ __launch_bounds__(256) void fc1_kernel(
    const u16* __restrict__ xb, const u16* __restrict__ w1b,
    const int* __restrict__ tok, const int* __restrict__ counts,
    const int* __restrict__ offsets, u16* __restrict__ h)
{
  int e = blockIdx.z;
  int Me = counts[e];
  int mbase = blockIdx.y * 128;
  if (mbase >= Me) return;
  int nbase = blockIdx.x * 128;
  int off = offsets[e];

  __shared__ u16 Als[128 * 64];
  __shared__ u16 Bls[128 * 64];

  int tid = threadIdx.x;
  int lane = tid & 63;
  int wid = tid >> 6;

  const u16* w1e = w1b + ((size_t)e * FDIM + nbase) * DIM;

  // per-lane staging sources: call c stages LDS elems [c*2048 + wid*512 + lane*8, +8)
  const u16* srcA[4];
  const u16* srcB[4];
#pragma unroll
  for (int c = 0; c < 4; ++c) {
    int epos = c * 2048 + wid * 512 + lane * 8;
    int r = epos >> 6;       // LDS row 0..127 (64 elems per row)
    int col = epos & 63;
    int rr = mbase + r; if (rr >= Me) rr = Me - 1;
    int trow = tok[off + rr];
    srcA[c] = xb + (size_t)trow * DIM + col;
    srcB[c] = w1e + (size_t)r * DIM + col;
  }

  f32x4 acc[4][4];
#pragma unroll
  for (int m = 0; m < 4; ++m)
#pragma unroll
    for (int n = 0; n < 4; ++n)
      acc[m][n] = (f32x4){0.f, 0.f, 0.f, 0.f};

  int wr = (wid >> 1) * 64;
  int wc = (wid & 1) * 64;
  int fr = lane & 15;
  int kg = lane >> 4;

  for (int kt = 0; kt < DIM; kt += 64) {
    __syncthreads();
#pragma unroll
    for (int c = 0; c < 4; ++c) {
      GLOAD16(srcA[c] + kt, &Als[c * 2048 + wid * 512]);
      GLOAD16(srcB[c] + kt, &Bls[c * 2048 + wid * 512]);
    }
    __syncthreads();
#pragma unroll
    for (int kk = 0; kk < 2; ++kk) {
      bf16x8 af[4], bfr[4];
#pragma unroll
      for (int m = 0; m < 4; ++m)
        af[m] = *(const bf16x8*)&Als[(wr + m * 16 + fr) * 64 + kk * 32 + kg * 8];
#pragma unroll
      for (int n = 0; n < 4; ++n)
        bfr[n] = *(const bf16x8*)&Bls[(wc + n * 16 + fr) * 64 + kk * 32 + kg * 8];
#pragma unroll
      for (int m = 0; m < 4; ++m)
#pragma unroll
        for (int n = 0; n < 4; ++n)
          acc[m][n] = __builtin_amdgcn_mfma_f32_16x16x32_bf16(af[m], bfr[n], acc[m][n], 0, 0, 0);
    }
  }

  int rb = kg * 4;
#pragma unroll
  for (int m = 0; m < 4; ++m) {
#pragma unroll
    for (int r = 0; r < 4; ++r) {
      int row = wr + m * 16 + rb + r;
      if (mbase + row < Me) {
        u16* dst = h + (size_t)(off + mbase + row) * FDIM + nbase + wc;
#pragma unroll
        for (int n = 0; n < 4; ++n) {
          float v = acc[m][n][r];
          v = 0.5f * v * (1.f + erff(v * 0.70710678118654752f));
          dst[n * 16 + fr] = f2b(v);
        }
      }
    }
  }
}

// ---------------- fc2: O[slot] = H[slot] @ W2t[e]^T, bf16 out (no atomics) ----------------
__global__ __launch_bounds__(256) void fc2_kernel(
    const u16* __restrict__ h, const u16* __restrict__ w2t,
    const int* __restrict__ counts, const int* __restrict__ offsets,
    u16* __restrict__ O)
{
  int e = blockIdx.z;
  int Me = counts[e];
  int mbase = blockIdx.y * 128;
  if (mbase >= Me) return;
  int nbase = blockIdx.x * 128;
  int off = offsets[e];

  __shared__ u16 Als[128 * 64];
  __shared__ u16 Bls[128 * 64];

  int tid = threadIdx.x;
  int lane = tid & 63;
  int wid = tid >> 6;

  const u16* w2e = w2t + ((size_t)e * DIM + nbase) * FDIM;

  const u16* srcA[4];
  const u16* srcB[4];
#pragma unroll
  for (int c = 0; c < 4; ++c) {
    int epos = c * 2048 + wid * 512 + lane * 8;
    int r = epos >> 6;
    int col = epos & 63;
    int rr = mbase + r; if (rr >= Me) rr = Me - 1;
    srcA[c] = h + (size_t)(off + rr) * FDIM + col;
    srcB[c] = w2e + (size_t)r * FDIM + col;
  }

  f32x4 acc[4][4];
#pragma unroll
  for (int m = 0; m < 4; ++m)
#pragma unroll
    for (int n = 0; n < 4; ++n)
      acc[m][n] = (f32x4){0.f, 0.f, 0.f, 0.f};

  int wr = (wid >> 1) * 64;
  int wc = (wid & 1) * 64;
  int fr = lane & 15;
  int kg = lane >> 4;

  for (int kt = 0; kt < FDIM; kt += 64) {
    __syncthreads();
#pragma unroll
    for (int c = 0; c < 4; ++c) {
      GLOAD16(srcA[c] + kt, &Als[c * 2048 + wid * 512]);
      GLOAD16(srcB[c] + kt, &Bls[c * 2048 + wid * 512]);
    }
    __syncthreads();
#pragma unroll
    for (int kk = 0; kk < 2; ++kk) {
      bf16x8 af[4], bfr[4];
#pragma unroll
      for (int m = 0; m < 4; ++m)
        af[m] = *(const bf16x8*)&Als[(wr + m * 16 + fr) * 64 + kk * 32 + kg * 8];
#pragma unroll
      for (int n = 0; n < 4; ++n)
        bfr[n] = *(const bf16x8*)&Bls[(wc + n * 16 + fr) * 64 + kk * 32 + kg * 8];
#pragma unroll
      for (int m = 0; m < 4; ++m)
#pragma unroll
        for (int n = 0; n < 4; ++n)
          acc[m][n] = __builtin_amdgcn_mfma_f32_16x16x32_bf16(af[m], bfr[n], acc[m][n], 0, 0, 0);
    }
  }

  int rb = kg * 4;
#pragma unroll
  for (int m = 0; m < 4; ++m) {
#pragma unroll
    for (int r = 0; r < 4; ++r) {
      int row = wr + m * 16 + rb + r;
      if (mbase + row < Me) {
        u16* dst = O + (size_t)(off + mbase + row) * DIM + nbase + wc;
#pragma unroll
        for (int n = 0; n < 4; ++n)
          dst[n * 16 + fr] = f2b(acc[m][n][r]);
      }
    }
  }
}

// ---------------- combine: y[t] = w0*O[s0] + w1*O[s1] ----------------
__global__ __launch_bounds__(256) void combine_kernel(
    const u16* __restrict__ O, const int* __restrict__ slot,
    const float* __restrict__ tokwgt, float* __restrict__ y)
{
  int idx = blockIdx.x * 256 + threadIdx.x;   // T*D/8 threads
  int t = idx >> 7;                            // 128 chunks of 8 per token
  int d8 = (idx & 127) << 3;
  int s0 = slot[2 * t], s1 = slot[2 * t + 1];
  float w0 = tokwgt[2 * t], w1 = tokwgt[2 * t + 1];
  bf16x8 a = *(const bf16x8*)(O + (size_t)s0 * DIM + d8);
  bf16x8 b = *(const bf16x8*)(O + (size_t)s1 * DIM + d8);
  float* dst = y + (size_t)t * DIM + d8;
  float4 o0, o1;
  o0.x = w0 * (float)a[0] + w1 * (float)b[0];
  o0.y = w0 * (float)a[1] + w1 * (float)b[1];
  o0.z = w0 * (float)a[2] + w1 * (float)b[2];
  o0.w = w0 * (float)a[3] + w1 * (float)b[3];
  o1.x = w0 * (float)a[4] + w1 * (float)b[4];
  o1.y = w0 * (float)a[5] + w1 * (float)b[5];
  o1.z = w0 * (float)a[6] + w1 * (float)b[6];
  o1.w = w0 * (float)a[7] + w1 * (float)b[7];
  *(float4*)dst = o0;
  *(float4*)(dst + 4) = o1;
}

extern "C" void kernel_launch(void* const* d_in, const int* in_sizes, int n_in,
                              void* d_out, int out_size, void* d_ws, size_t ws_size,
                              hipStream_t stream)
{
  const float* x  = (const float*)d_in[0];
  const float* wg = (const float*)d_in[1];
  const float* w1 = (const float*)d_in[2];
  const float* w2 = (const float*)d_in[3];
  float* y = (float*)d_out;

  char* ws = (char*)d_ws;
  size_t o = 0;
  u16* h      = (u16*)(ws + o);   o += (size_t)8192 * FDIM * 2;        // 33.55 MB
  u16* w2t    = (u16*)(ws + o);   o += (size_t)NEXP * DIM * FDIM * 2;  // 33.55 MB
  u16* xb     = (u16*)(ws + o);   o += (size_t)T_TOK * DIM * 2;        //  8.39 MB
  u16* w1b    = (u16*)(ws + o);   o += (size_t)NEXP * FDIM * DIM * 2;  // 33.55 MB
  u16* O      = w1b;  // aliased: w1b dead after fc1, O written by fc2 (16.78 MB)
  int*   tokexp = (int*)(ws + o); o += (size_t)T_TOK * 2 * 4;
  float* tokwgt = (float*)(ws + o); o += (size_t)T_TOK * 2 * 4;
  int*   tok    = (int*)(ws + o); o += (size_t)T_TOK * 2 * 4;
  int*   slot   = (int*)(ws + o); o += (size_t)T_TOK * 2 * 4;
  int*   counts = (int*)(ws + o); o += 128;
  int*   offsets= (int*)(ws + o); o += 128;
  int*   cursor = (int*)(ws + o); o += 128;

  hipMemsetAsync(counts, 0, 384, stream);  // counts + offsets + cursor

  gating_kernel<<<T_TOK, 256, 0, stream>>>(x, wg, tokexp, tokwgt, counts);
  prefix_kernel<<<1, 64, 0, stream>>>(counts, offsets);
  scatter_kernel<<<T_TOK / 256, 256, 0, stream>>>(tokexp, offsets, cursor, tok, slot);

  convert_kernel<<<(T_TOK * DIM / 8 + 255) / 256, 256, 0, stream>>>(x, xb, T_TOK * DIM / 8);
  convert_kernel<<<(NEXP * FDIM * DIM / 8 + 255) / 256, 256, 0, stream>>>(w1, w1b, NEXP * FDIM * DIM / 8);
  transpose_kernel<<<dim3(DIM / 32, FDIM / 32, NEXP), 256, 0, stream>>>(w2, w2t);

  fc1_kernel<<<dim3(FDIM / 128, T_TOK / 128, NEXP), 256, 0, stream>>>(xb, w1b, tok, counts, offsets, h);
  fc2_kernel<<<dim3(DIM / 128, T_TOK / 128, NEXP), 256, 0, stream>>>(h, w2t, counts, offsets, O);
  combine_kernel<<<T_TOK * DIM / 8 / 256, 256, 0, stream>>>(O, slot, tokwgt, y);
}

// Round 3
// 248.374 us; speedup vs baseline: 1.5287x; 1.4577x over previous
//
#include <hip/hip_runtime.h>

#define T_TOK 4096
#define DIM   1024
#define FDIM  2048
#define NEXP  8

typedef unsigned short u16;
typedef unsigned int   u32;
typedef __bf16 bf16x8 __attribute__((ext_vector_type(8)));
typedef float  f32x4  __attribute__((ext_vector_type(4)));

__device__ __forceinline__ u16 f2b(float f) {
  __bf16 b = (__bf16)f;
  return __builtin_bit_cast(u16, b);
}
__device__ __forceinline__ u32 pk(float a, float b) {
  return (u32)f2b(a) | ((u32)f2b(b) << 16);
}

// async global->LDS, 16B per lane; LDS dest is wave-uniform base + lane*16
#define GLOAD16(gsrc, ldst) \
  __builtin_amdgcn_global_load_lds((const __attribute__((address_space(1))) void*)(gsrc), \
                                   (__attribute__((address_space(3))) void*)(ldst), 16, 0, 0)

// ---------------- gating: 1 token per wave; logits -> softmax -> top2; fused x->bf16 ----
__global__ __launch_bounds__(256) void gating_kernel(
    const float* __restrict__ x, const float* __restrict__ wg,
    int* __restrict__ tokexp, float* __restrict__ tokwgt, u16* __restrict__ xb)
{
  int wid = threadIdx.x >> 6, lane = threadIdx.x & 63;
  int t = blockIdx.x * 4 + wid;
  const float4* xr = (const float4*)(x + (size_t)t * DIM) + lane * 4;
  float4 xv[4];
#pragma unroll
  for (int j = 0; j < 4; ++j) xv[j] = xr[j];

  // fused conversion: write this token's row as bf16
  u16* xd = xb + (size_t)t * DIM + lane * 16;
  uint4 lo, hi;
  lo.x = pk(xv[0].x, xv[0].y); lo.y = pk(xv[0].z, xv[0].w);
  lo.z = pk(xv[1].x, xv[1].y); lo.w = pk(xv[1].z, xv[1].w);
  hi.x = pk(xv[2].x, xv[2].y); hi.y = pk(xv[2].z, xv[2].w);
  hi.z = pk(xv[3].x, xv[3].y); hi.w = pk(xv[3].z, xv[3].w);
  *(uint4*)xd = lo;
  *(uint4*)(xd + 8) = hi;

  float logit[NEXP];
#pragma unroll
  for (int e = 0; e < NEXP; ++e) {
    const float4* wr = (const float4*)(wg + (size_t)e * DIM) + lane * 4;
    float s = 0.f;
#pragma unroll
    for (int j = 0; j < 4; ++j) {
      float4 wv = wr[j];
      s += xv[j].x * wv.x + xv[j].y * wv.y + xv[j].z * wv.z + xv[j].w * wv.w;
    }
#pragma unroll
    for (int d = 32; d > 0; d >>= 1) s += __shfl_down(s, d, 64);
    logit[e] = s;
  }
  if (lane == 0) {
    float mx = -1e30f;
#pragma unroll
    for (int e = 0; e < NEXP; ++e) mx = fmaxf(mx, logit[e]);
    float p[NEXP]; float s = 0.f;
#pragma unroll
    for (int e = 0; e < NEXP; ++e) { p[e] = expf(logit[e] - mx); s += p[e]; }
    float inv = 1.f / s;
#pragma unroll
    for (int e = 0; e < NEXP; ++e) p[e] *= inv;
    int e0 = 0;
#pragma unroll
    for (int e = 1; e < NEXP; ++e) if (p[e] > p[e0]) e0 = e;
    int e1 = (e0 == 0) ? 1 : 0;
#pragma unroll
    for (int e = 0; e < NEXP; ++e) if (e != e0 && p[e] > p[e1]) e1 = e;
    tokexp[2 * t]     = e0;
    tokexp[2 * t + 1] = e1;
    tokwgt[2 * t]     = p[e0];
    tokwgt[2 * t + 1] = p[e1];
  }
}

// ---------------- plan: single block; histogram + offsets + stable scatter ----------------
__global__ __launch_bounds__(256) void plan_kernel(
    const int* __restrict__ tokexp,
    int* __restrict__ counts, int* __restrict__ offsets,
    int* __restrict__ tok, int* __restrict__ slot)
{
  __shared__ int hist[256][NEXP];
  __shared__ int soff[NEXP];
  int tid = threadIdx.x;
  int ex[32];
  int loc[NEXP];
#pragma unroll
  for (int e = 0; e < NEXP; ++e) loc[e] = 0;
#pragma unroll
  for (int j = 0; j < 32; ++j) {
    ex[j] = tokexp[tid * 32 + j];
#pragma unroll
    for (int e = 0; e < NEXP; ++e) loc[e] += (ex[j] == e);
  }
#pragma unroll
  for (int e = 0; e < NEXP; ++e) hist[tid][e] = loc[e];
  __syncthreads();
  if (tid < NEXP) {
    int s = 0;
    for (int i = 0; i < 256; ++i) { int v = hist[i][tid]; hist[i][tid] = s; s += v; }
    counts[tid] = s;
  }
  __syncthreads();
  if (tid == 0) {
    int s = 0;
#pragma unroll
    for (int e = 0; e < NEXP; ++e) { soff[e] = s; offsets[e] = s; s += counts[e]; }
  }
  __syncthreads();
  int cur[NEXP];
#pragma unroll
  for (int e = 0; e < NEXP; ++e) cur[e] = soff[e] + hist[tid][e];
#pragma unroll
  for (int j = 0; j < 32; ++j) {
    int a = tid * 32 + j;
    int r = 0;
#pragma unroll
    for (int e = 0; e < NEXP; ++e) if (ex[j] == e) r = cur[e]++;
    tok[r] = a >> 1;
    slot[a] = r;
  }
}

// generic fp32 -> bf16, 8 elems/thread
__global__ __launch_bounds__(256) void convert_kernel(
    const float* __restrict__ src, u16* __restrict__ dst, int n8)
{
  int i = blockIdx.x * 256 + threadIdx.x;
  if (i >= n8) return;
  const float4* s = (const float4*)(src + (size_t)i * 8);
  float4 v0 = s[0], v1 = s[1];
  uint4 w;
  w.x = pk(v0.x, v0.y); w.y = pk(v0.z, v0.w);
  w.z = pk(v1.x, v1.y); w.w = pk(v1.z, v1.w);
  *(uint4*)(dst + (size_t)i * 8) = w;
}

// w2 [E][F][D] fp32 -> w2t [E][D][F] bf16
__global__ __launch_bounds__(256) void transpose_kernel(
    const float* __restrict__ w2, u16* __restrict__ w2t)
{
  __shared__ float tile[32][33];
  int e = blockIdx.z;
  int d0 = blockIdx.x * 32;
  int f0 = blockIdx.y * 32;
  int tx = threadIdx.x & 31;
  int ty = threadIdx.x >> 5;  // 0..7
  const float* src = w2 + ((size_t)e * FDIM + f0) * DIM + d0;
#pragma unroll
  for (int j = 0; j < 4; ++j)
    tile[ty + 8 * j][tx] = src[(size_t)(ty + 8 * j) * DIM + tx];
  __syncthreads();
  u16* dst = w2t + ((size_t)e * DIM + d0) * FDIM + f0;
#pragma unroll
  for (int j = 0; j < 4; ++j)
    dst[(size_t)(ty + 8 * j) * FDIM + tx] = f2b(tile[tx][ty + 8 * j]);
}

// ---------------- fc1: h = gelu( Xb_gathered @ W1b[e]^T ), bf16 out ----------------
__global__ __launch_bounds__(256) void fc1_kernel(
    const u16* __restrict__ xb, const u16* __restrict__ w1b,
    const int* __restrict__ tok, const int* __restrict__ counts,
    const int* __restrict__ offsets, u16* __restrict__ h)
{
  int e = blockIdx.z;
  int Me = counts[e];
  int mbase = blockIdx.y * 128;
  if (mbase >= Me) return;
  int nbase = blockIdx.x * 128;
  int off = offsets[e];

  __shared__ u16 Als[128 * 64];
  __shared__ u16 Bls[128 * 64];

  int tid = threadIdx.x;
  int lane = tid & 63;
  int wid = tid >> 6;

  const u16* w1e = w1b + ((size_t)e * FDIM + nbase) * DIM;

  const u16* srcA[4];
  const u16* srcB[4];
#pragma unroll
  for (int c = 0; c < 4; ++c) {
    int epos = c * 2048 + wid * 512 + lane * 8;
    int r = epos >> 6;
    int col = epos & 63;
    int rr = mbase + r; if (rr >= Me) rr = Me - 1;
    int trow = tok[off + rr];
    srcA[c] = xb + (size_t)trow * DIM + col;
    srcB[c] = w1e + (size_t)r * DIM + col;
  }

  f32x4 acc[4][4];
#pragma unroll
  for (int m = 0; m < 4; ++m)
#pragma unroll
    for (int n = 0; n < 4; ++n)
      acc[m][n] = (f32x4){0.f, 0.f, 0.f, 0.f};

  int wr = (wid >> 1) * 64;
  int wc = (wid & 1) * 64;
  int fr = lane & 15;
  int kg = lane >> 4;

  for (int kt = 0; kt < DIM; kt += 64) {
    __syncthreads();
#pragma unroll
    for (int c = 0; c < 4; ++c) {
      GLOAD16(srcA[c] + kt, &Als[c * 2048 + wid * 512]);
      GLOAD16(srcB[c] + kt, &Bls[c * 2048 + wid * 512]);
    }
    __syncthreads();
#pragma unroll
    for (int kk = 0; kk < 2; ++kk) {
      bf16x8 af[4], bfr[4];
#pragma unroll
      for (int m = 0; m < 4; ++m)
        af[m] = *(const bf16x8*)&Als[(wr + m * 16 + fr) * 64 + kk * 32 + kg * 8];
#pragma unroll
      for (int n = 0; n < 4; ++n)
        bfr[n] = *(const bf16x8*)&Bls[(wc + n * 16 + fr) * 64 + kk * 32 + kg * 8];
#pragma unroll
      for (int m = 0; m < 4; ++m)
#pragma unroll
        for (int n = 0; n < 4; ++n)
          acc[m][n] = __builtin_amdgcn_mfma_f32_16x16x32_bf16(af[m], bfr[n], acc[m][n], 0, 0, 0);
    }
  }

  int rb = kg * 4;
#pragma unroll
  for (int m = 0; m < 4; ++m) {
#pragma unroll
    for (int r = 0; r < 4; ++r) {
      int row = wr + m * 16 + rb + r;
      if (mbase + row < Me) {
        u16* dst = h + (size_t)(off + mbase + row) * FDIM + nbase + wc;
#pragma unroll
        for (int n = 0; n < 4; ++n) {
          float v = acc[m][n][r];
          v = 0.5f * v * (1.f + erff(v * 0.70710678118654752f));
          dst[n * 16 + fr] = f2b(v);
        }
      }
    }
  }
}

// ---------------- fc2: O[slot] = H[slot] @ W2t[e]^T, bf16 out (no atomics) ----------------
__global__ __launch_bounds__(256) void fc2_kernel(
    const u16* __restrict__ h, const u16* __restrict__ w2t,
    const int* __restrict__ counts, const int* __restrict__ offsets,
    u16* __restrict__ O)
{
  int e = blockIdx.z;
  int Me = counts[e];
  int mbase = blockIdx.y * 128;
  if (mbase >= Me) return;
  int nbase = blockIdx.x * 128;
  int off = offsets[e];

  __shared__ u16 Als[128 * 64];
  __shared__ u16 Bls[128 * 64];

  int tid = threadIdx.x;
  int lane = tid & 63;
  int wid = tid >> 6;

  const u16* w2e = w2t + ((size_t)e * DIM + nbase) * FDIM;

  const u16* srcA[4];
  const u16* srcB[4];
#pragma unroll
  for (int c = 0; c < 4; ++c) {
    int epos = c * 2048 + wid * 512 + lane * 8;
    int r = epos >> 6;
    int col = epos & 63;
    int rr = mbase + r; if (rr >= Me) rr = Me - 1;
    srcA[c] = h + (size_t)(off + rr) * FDIM + col;
    srcB[c] = w2e + (size_t)r * FDIM + col;
  }

  f32x4 acc[4][4];
#pragma unroll
  for (int m = 0; m < 4; ++m)
#pragma unroll
    for (int n = 0; n < 4; ++n)
      acc[m][n] = (f32x4){0.f, 0.f, 0.f, 0.f};

  int wr = (wid >> 1) * 64;
  int wc = (wid & 1) * 64;
  int fr = lane & 15;
  int kg = lane >> 4;

  for (int kt = 0; kt < FDIM; kt += 64) {
    __syncthreads();
#pragma unroll
    for (int c = 0; c < 4; ++c) {
      GLOAD16(srcA[c] + kt, &Als[c * 2048 + wid * 512]);
      GLOAD16(srcB[c] + kt, &Bls[c * 2048 + wid * 512]);
    }
    __syncthreads();
#pragma unroll
    for (int kk = 0; kk < 2; ++kk) {
      bf16x8 af[4], bfr[4];
#pragma unroll
      for (int m = 0; m < 4; ++m)
        af[m] = *(const bf16x8*)&Als[(wr + m * 16 + fr) * 64 + kk * 32 + kg * 8];
#pragma unroll
      for (int n = 0; n < 4; ++n)
        bfr[n] = *(const bf16x8*)&Bls[(wc + n * 16 + fr) * 64 + kk * 32 + kg * 8];
#pragma unroll
      for (int m = 0; m < 4; ++m)
#pragma unroll
        for (int n = 0; n < 4; ++n)
          acc[m][n] = __builtin_amdgcn_mfma_f32_16x16x32_bf16(af[m], bfr[n], acc[m][n], 0, 0, 0);
    }
  }

  int rb = kg * 4;
#pragma unroll
  for (int m = 0; m < 4; ++m) {
#pragma unroll
    for (int r = 0; r < 4; ++r) {
      int row = wr + m * 16 + rb + r;
      if (mbase + row < Me) {
        u16* dst = O + (size_t)(off + mbase + row) * DIM + nbase + wc;
#pragma unroll
        for (int n = 0; n < 4; ++n)
          dst[n * 16 + fr] = f2b(acc[m][n][r]);
      }
    }
  }
}

// ---------------- combine: y[t] = w0*O[s0] + w1*O[s1] ----------------
__global__ __launch_bounds__(256) void combine_kernel(
    const u16* __restrict__ O, const int* __restrict__ slot,
    const float* __restrict__ tokwgt, float* __restrict__ y)
{
  int idx = blockIdx.x * 256 + threadIdx.x;   // T*D/8 threads
  int t = idx >> 7;
  int d8 = (idx & 127) << 3;
  int s0 = slot[2 * t], s1 = slot[2 * t + 1];
  float w0 = tokwgt[2 * t], w1 = tokwgt[2 * t + 1];
  bf16x8 a = *(const bf16x8*)(O + (size_t)s0 * DIM + d8);
  bf16x8 b = *(const bf16x8*)(O + (size_t)s1 * DIM + d8);
  float* dst = y + (size_t)t * DIM + d8;
  float4 o0, o1;
  o0.x = w0 * (float)a[0] + w1 * (float)b[0];
  o0.y = w0 * (float)a[1] + w1 * (float)b[1];
  o0.z = w0 * (float)a[2] + w1 * (float)b[2];
  o0.w = w0 * (float)a[3] + w1 * (float)b[3];
  o1.x = w0 * (float)a[4] + w1 * (float)b[4];
  o1.y = w0 * (float)a[5] + w1 * (float)b[5];
  o1.z = w0 * (float)a[6] + w1 * (float)b[6];
  o1.w = w0 * (float)a[7] + w1 * (float)b[7];
  *(float4*)dst = o0;
  *(float4*)(dst + 4) = o1;
}

extern "C" void kernel_launch(void* const* d_in, const int* in_sizes, int n_in,
                              void* d_out, int out_size, void* d_ws, size_t ws_size,
                              hipStream_t stream)
{
  const float* x  = (const float*)d_in[0];
  const float* wg = (const float*)d_in[1];
  const float* w1 = (const float*)d_in[2];
  const float* w2 = (const float*)d_in[3];
  float* y = (float*)d_out;

  char* ws = (char*)d_ws;
  size_t o = 0;
  u16* h      = (u16*)(ws + o);   o += (size_t)8192 * FDIM * 2;        // 33.55 MB
  u16* w2t    = (u16*)(ws + o);   o += (size_t)NEXP * DIM * FDIM * 2;  // 33.55 MB
  u16* xb     = (u16*)(ws + o);   o += (size_t)T_TOK * DIM * 2;        //  8.39 MB
  u16* w1b    = (u16*)(ws + o);   o += (size_t)NEXP * FDIM * DIM * 2;  // 33.55 MB
  u16* O      = w1b;  // aliased: w1b dead after fc1, O written by fc2 (16.78 MB)
  int*   tokexp = (int*)(ws + o); o += (size_t)T_TOK * 2 * 4;
  float* tokwgt = (float*)(ws + o); o += (size_t)T_TOK * 2 * 4;
  int*   tok    = (int*)(ws + o); o += (size_t)T_TOK * 2 * 4;
  int*   slot   = (int*)(ws + o); o += (size_t)T_TOK * 2 * 4;
  int*   counts = (int*)(ws + o); o += 128;
  int*   offsets= (int*)(ws + o); o += 128;

  gating_kernel<<<T_TOK / 4, 256, 0, stream>>>(x, wg, tokexp, tokwgt, xb);
  plan_kernel<<<1, 256, 0, stream>>>(tokexp, counts, offsets, tok, slot);

  convert_kernel<<<(NEXP * FDIM * DIM / 8 + 255) / 256, 256, 0, stream>>>(w1, w1b, NEXP * FDIM * DIM / 8);
  transpose_kernel<<<dim3(DIM / 32, FDIM / 32, NEXP), 256, 0, stream>>>(w2, w2t);

  fc1_kernel<<<dim3(FDIM / 128, T_TOK / 128, NEXP), 256, 0, stream>>>(xb, w1b, tok, counts, offsets, h);
  fc2_kernel<<<dim3(DIM / 128, T_TOK / 128, NEXP), 256, 0, stream>>>(h, w2t, counts, offsets, O);
  combine_kernel<<<T_TOK * DIM / 8 / 256, 256, 0, stream>>>(O, slot, tokwgt, y);
}